// Round 2
// baseline (809.665 us; speedup 1.0000x reference)
//
#include <hip/hip_runtime.h>
#include <hip/hip_bf16.h>

// ---- problem constants ----
#define NTOK_B   32768      // tokens per batch (H*W*D)
#define TOK_TOT  65536      // B * NTOK_B
#define CDIM     256
#define NHEAD    8
#define DHEAD    32
#define FFDIM    1024
#define LN_EPS   1e-3f

typedef __attribute__((ext_vector_type(8))) short bf16x8;   // 8 bf16 in 4 VGPRs (guide §3)
typedef __attribute__((ext_vector_type(4))) float f32x4;

__device__ __forceinline__ float bf2f(short s) {
    union { unsigned u; float f; } v; v.u = ((unsigned)(unsigned short)s) << 16; return v.f;
}
__device__ __forceinline__ short f2bf(float f) {
    union { float f; unsigned u; } v; v.f = f;
    unsigned r = (v.u + 0x7FFFu + ((v.u >> 16) & 1u)) >> 16;
    return (short)r;
}

// ---------------------------------------------------------------------------
// Weight transpose + fp32->bf16: out[n][k] = bf16(in[k][n]). K,N multiples of 32.
// ---------------------------------------------------------------------------
__global__ __launch_bounds__(256) void transpose_k(const float* __restrict__ in,
                                                   short* __restrict__ out, int K, int N)
{
    __shared__ float t[32][33];
    int kt = blockIdx.x * 32, nt = blockIdx.y * 32;
    int tx = threadIdx.x, ty = threadIdx.y;          // blockDim = (32,8)
#pragma unroll
    for (int i = 0; i < 4; ++i)
        t[ty + i * 8][tx] = in[(long)(kt + ty + i * 8) * N + nt + tx];
    __syncthreads();
#pragma unroll
    for (int i = 0; i < 4; ++i)
        out[(long)(nt + ty + i * 8) * K + kt + tx] = f2bf(t[tx][ty + i * 8]);
}

// ---------------------------------------------------------------------------
// MFMA GEMM: Out[M][N] = act(X[M][K](ld=ldx) @ Wt[N][K]^T + bias)
// X is fp32 (XF32=1, converted to bf16 during staging) or bf16 (XF32=0).
// Out is fp32 (OF32=1) or bf16 (OF32=0). bias is fp32.
// 128x128 block tile, BK=32, 4 waves of 4x4 mfma_f32_16x16x32_bf16 tiles.
// LDS in FRAGMENT ORDER: chunk idx = ti*64 + quad*16 + m, 16B each, so both
// ds_write (idx=tid) and ds_read (idx=tile*64+lane) are lane-consecutive.
// A-frag: A[m=lane&15][k=(lane>>4)*8+j]; B-frag: B-row n=lane&15 of Wt;
// C/D: col=lane&15, row=(lane>>4)*4+reg (m89/m91-verified layouts).
// ACT: 0 = none, 1 = exact GELU. Grid: (N/128, M/128), 256 threads.
// ---------------------------------------------------------------------------
template<int ACT, int XF32, int OF32>
__global__ __launch_bounds__(256) void gemm_bt(const void* __restrict__ Xv,
                                               const short* __restrict__ Wt,
                                               const float* __restrict__ bias,
                                               void* __restrict__ Outv,
                                               int N, int K, int ldx, int ldo)
{
    __shared__ __align__(16) short As[4096];   // 8 KB: 8 row-tiles * 64 lanes * 8 bf16
    __shared__ __align__(16) short Bs[4096];
    const int tid  = threadIdx.x;
    const int lane = tid & 63;
    const int wave = tid >> 6;
    const int wm   = (wave >> 1) * 4;   // A row-tile base (0 or 4)
    const int wn   = (wave & 1) * 4;    // B col-tile base (0 or 4)
    const long m0  = (long)blockIdx.y * 128;
    const int  n0  = blockIdx.x * 128;

    f32x4 acc[4][4];
#pragma unroll
    for (int i = 0; i < 4; ++i)
#pragma unroll
        for (int j = 0; j < 4; ++j) acc[i][j] = (f32x4)0.0f;

    for (int k0 = 0; k0 < K; k0 += 32) {
        __syncthreads();
#pragma unroll
        for (int p = 0; p < 2; ++p) {
            int idx = tid + p * 256;
            int ti = idx >> 6, q = (idx >> 4) & 3, m = idx & 15;
            int row = ti * 16 + m;
            if (XF32) {
                const float* xp = (const float*)Xv + (m0 + row) * (long)ldx + k0 + q * 8;
                float4 xa = *(const float4*)xp;
                float4 xb = *(const float4*)(xp + 4);
                short tmp[8];
                tmp[0] = f2bf(xa.x); tmp[1] = f2bf(xa.y); tmp[2] = f2bf(xa.z); tmp[3] = f2bf(xa.w);
                tmp[4] = f2bf(xb.x); tmp[5] = f2bf(xb.y); tmp[6] = f2bf(xb.z); tmp[7] = f2bf(xb.w);
                *(int4*)(As + idx * 8) = *(const int4*)tmp;
            } else {
                *(int4*)(As + idx * 8) =
                    *(const int4*)((const short*)Xv + (m0 + row) * (long)ldx + k0 + q * 8);
            }
            *(int4*)(Bs + idx * 8) = *(const int4*)(Wt + (long)(n0 + row) * K + k0 + q * 8);
        }
        __syncthreads();
        bf16x8 a[4], b[4];
#pragma unroll
        for (int i = 0; i < 4; ++i) a[i] = *(const bf16x8*)(As + ((wm + i) * 64 + lane) * 8);
#pragma unroll
        for (int j = 0; j < 4; ++j) b[j] = *(const bf16x8*)(Bs + ((wn + j) * 64 + lane) * 8);
#pragma unroll
        for (int i = 0; i < 4; ++i)
#pragma unroll
            for (int j = 0; j < 4; ++j)
                acc[i][j] = __builtin_amdgcn_mfma_f32_16x16x32_bf16(a[i], b[j], acc[i][j], 0, 0, 0);
    }

    const int crow0 = (wave >> 1) * 64 + (lane >> 4) * 4;
    const int ccol0 = (wave & 1) * 64 + (lane & 15);
#pragma unroll
    for (int j = 0; j < 4; ++j) {
        int col = n0 + ccol0 + j * 16;
        float bb = bias[col];
#pragma unroll
        for (int i = 0; i < 4; ++i) {
            long row = m0 + crow0 + i * 16;
#pragma unroll
            for (int r = 0; r < 4; ++r) {
                float v = acc[i][j][r] + bb;
                if (ACT == 1) v = 0.5f * v * (1.0f + erff(v * 0.70710678118654752f));
                if (OF32) ((float*)Outv)[(row + r) * (long)ldo + col] = v;
                else      ((short*)Outv)[(row + r) * (long)ldo + col] = f2bf(v);
            }
        }
    }
}

// ---------------------------------------------------------------------------
// K column softmax stats (softmax over tokens per (b, channel)).
// Phase 1: per-(b, 256-token chunk) online (max, sumexp) per channel.
// ---------------------------------------------------------------------------
__global__ __launch_bounds__(256) void kstats_part(const short* __restrict__ QKV,
                                                   float* __restrict__ pm, float* __restrict__ ps)
{
    int b = blockIdx.y, ch = blockIdx.x, c = threadIdx.x;
    const short* Kp = QKV + ((long)b * NTOK_B + ch * 256) * 768 + 256 + c;
    float m = -1e30f, s = 0.0f;
    for (int n = 0; n < 256; ++n) {
        float x = bf2f(Kp[(long)n * 768]);
        if (x > m) { s = s * __expf(m - x) + 1.0f; m = x; }
        else       { s += __expf(x - m); }
    }
    pm[((long)b * 128 + ch) * 256 + c] = m;
    ps[((long)b * 128 + ch) * 256 + c] = s;
}

__global__ __launch_bounds__(256) void kstats_fin(const float* __restrict__ pm,
                                                  const float* __restrict__ ps,
                                                  float* __restrict__ kmax, float* __restrict__ ksum)
{
    int b = blockIdx.x, c = threadIdx.x;
    float m = -1e30f, s = 0.0f;
    for (int ch = 0; ch < 128; ++ch) {
        float mi = pm[((long)b * 128 + ch) * 256 + c];
        float si = ps[((long)b * 128 + ch) * 256 + c];
        if (mi > m) { s = s * __expf(m - mi) + si; m = mi; }
        else        { s += si * __expf(mi - m); }
    }
    kmax[b * 256 + c] = m;
    ksum[b * 256 + c] = s;
}

// ---------------------------------------------------------------------------
// context_raw[b][h][d][e] = sum_n exp(K[b,n,h*32+d] - kmax) * V[b,n,h*32+e]
// (1/Z folded later). Grid (32 token-chunks, NH, B), 256 thr. fp32 atomics.
// ---------------------------------------------------------------------------
__global__ __launch_bounds__(256) void context_k(const short* __restrict__ QKV,
                                                 const float* __restrict__ kmax,
                                                 float* __restrict__ ctx)
{
    int b = blockIdx.z, h = blockIdx.y;
    long tok0 = (long)b * NTOK_B + (long)blockIdx.x * 1024;
    __shared__ __align__(16) float kb[8][32], vb[8][32];
    __shared__ float smax[32];
    int tid = threadIdx.x;
    if (tid < 32) smax[tid] = kmax[b * 256 + h * 32 + tid];
    int d = tid >> 3, e0 = (tid & 7) * 4;       // thread owns (d, e0..e0+3)
    int tl = tid >> 5, r = tid & 31;            // staging role
    float a0 = 0, a1 = 0, a2 = 0, a3 = 0;
    for (int g = 0; g < 128; ++g) {
        __syncthreads();
        long trow = tok0 + g * 8 + tl;
        if (r < 16) {
            int dd = r * 2;
            const short* Kp = QKV + trow * 768 + 256 + h * 32 + dd;
            kb[tl][dd]     = __expf(bf2f(Kp[0]) - smax[dd]);
            kb[tl][dd + 1] = __expf(bf2f(Kp[1]) - smax[dd + 1]);
        } else {
            int ee = (r - 16) * 2;
            const short* Vp = QKV + trow * 768 + 512 + h * 32 + ee;
            vb[tl][ee]     = bf2f(Vp[0]);
            vb[tl][ee + 1] = bf2f(Vp[1]);
        }
        __syncthreads();
#pragma unroll
        for (int tt = 0; tt < 8; ++tt) {
            float kd = kb[tt][d];
            float4 v = *(const float4*)&vb[tt][e0];
            a0 += kd * v.x; a1 += kd * v.y; a2 += kd * v.z; a3 += kd * v.w;
        }
    }
    float* cp = ctx + (((long)b * 8 + h) * 32 + d) * 32 + e0;
    atomicAdd(cp + 0, a0); atomicAdd(cp + 1, a1);
    atomicAdd(cp + 2, a2); atomicAdd(cp + 3, a3);
}

// ---------------------------------------------------------------------------
// Fused: q softmax (over dh) -> attn = q_norm @ (ctx/Z) -> + inq(fp32) -> LN1
// -> x (bf16). Block = 128 tokens (8 sub-batches of 16), 256 threads.
// ctx/Z cached in registers per (h,e) thread. LDS ~38.5 KB.
// ---------------------------------------------------------------------------
__global__ __launch_bounds__(256) void attn_ln1(const short* __restrict__ QKV,
                                                const float* __restrict__ qin,
                                                const float* __restrict__ ctx,
                                                const float* __restrict__ ksum,
                                                const float* __restrict__ g1,
                                                const float* __restrict__ b1,
                                                short* __restrict__ xout)
{
    long tok0blk = (long)blockIdx.x * 128;
    int b = (int)(tok0blk >> 15);
    __shared__ __align__(16) float qn[16][292];  // q_norm rows, head stride 36
    __shared__ __align__(16) float xb[16][292];  // attn + residual rows
    __shared__ float red[16][8][2];
    __shared__ float mr[16][2];
    int tid = threadIdx.x;
    int h = tid >> 5, e = tid & 31;

    float cregs[32];
    {
        const float* cp = ctx + ((long)(b * 8 + h) * 32) * 32 + e;
        const float* zs = ksum + b * 256 + h * 32;
#pragma unroll
        for (int d = 0; d < 32; ++d) cregs[d] = cp[d * 32] / zs[d];
    }

    for (int sub = 0; sub < 8; ++sub) {
        long tok0 = tok0blk + sub * 16;
        // ---- phase A: q softmax over dh=32 (threads 0..127: 16 tok x 8 heads)
        if (tid < 128) {
            int tA = tid >> 3, hA = tid & 7;
            const short* Qp = QKV + (tok0 + tA) * 768 + hA * 32;
            short qv[32];
            *(int4*)&qv[0]  = *(const int4*)(Qp);
            *(int4*)&qv[8]  = *(const int4*)(Qp + 8);
            *(int4*)&qv[16] = *(const int4*)(Qp + 16);
            *(int4*)&qv[24] = *(const int4*)(Qp + 24);
            float f[32]; float mx = -1e30f;
#pragma unroll
            for (int i = 0; i < 32; ++i) { f[i] = bf2f(qv[i]); mx = fmaxf(mx, f[i]); }
            float s = 0.0f;
#pragma unroll
            for (int i = 0; i < 32; ++i) { f[i] = __expf(f[i] - mx); s += f[i]; }
            float inv = 1.0f / s;
            float* qrow = &qn[tA][hA * 36];
#pragma unroll
            for (int i = 0; i < 32; ++i) qrow[i] = f[i] * inv;
        }
        __syncthreads();
        // ---- phase B: attn + residual (all 256 threads: thread = (h,e))
        {
            int cch = h * 32 + e;
#pragma unroll 2
            for (int t = 0; t < 16; ++t) {
                const float4* qr = (const float4*)&qn[t][h * 36];
                float a = 0.0f;
#pragma unroll
                for (int d4 = 0; d4 < 8; ++d4) {
                    float4 qv = qr[d4];
                    a += qv.x * cregs[d4 * 4 + 0] + qv.y * cregs[d4 * 4 + 1]
                       + qv.z * cregs[d4 * 4 + 2] + qv.w * cregs[d4 * 4 + 3];
                }
                float iv = qin[(tok0 + t) * 256 + cch];
                xb[t][cch] = a + iv;
            }
        }
        __syncthreads();
        // ---- phase C: LN partial sums (threads 0..127: 16 tok x 8 segs)
        if (tid < 128) {
            int tC = tid & 15, sC = tid >> 4;
            float s = 0, ss = 0;
            const float* xr = &xb[tC][sC * 32];
#pragma unroll
            for (int i = 0; i < 32; ++i) { float v = xr[i]; s += v; ss += v * v; }
            red[tC][sC][0] = s; red[tC][sC][1] = ss;
        }
        __syncthreads();
        if (tid < 16) {
            float s = 0, ss = 0;
#pragma unroll
            for (int k = 0; k < 8; ++k) { s += red[tid][k][0]; ss += red[tid][k][1]; }
            float mean = s * (1.0f / 256.0f);
            float var  = ss * (1.0f / 256.0f) - mean * mean;
            mr[tid][0] = mean; mr[tid][1] = rsqrtf(var + LN_EPS);
        }
        __syncthreads();
        // ---- phase D: normalize + store bf16
        if (tid < 128) {
            int tC = tid & 15, sC = tid >> 4;
            float mean = mr[tC][0], rstd = mr[tC][1];
            const float* xr = &xb[tC][sC * 32];
            short ov[32];
#pragma unroll
            for (int i = 0; i < 32; ++i) {
                int c = sC * 32 + i;
                float v = (xr[i] - mean) * rstd * g1[c] + b1[c];
                ov[i] = f2bf(v);
            }
            int4* op = (int4*)(xout + (tok0 + tC) * 256 + sC * 32);
            op[0] = *(int4*)&ov[0];  op[1] = *(int4*)&ov[8];
            op[2] = *(int4*)&ov[16]; op[3] = *(int4*)&ov[24];
        }
        __syncthreads();
    }
}

// ---------------------------------------------------------------------------
// LN2 in-place on d_out (fp32): out = LN(x + y), y = d_out (ff2 output, fp32),
// x = xbuf (bf16). One wave per token, lane owns 4 channels.
// ---------------------------------------------------------------------------
__global__ __launch_bounds__(256) void ln2_k(const short* __restrict__ xbuf,
                                             float* __restrict__ out,
                                             const float* __restrict__ g2,
                                             const float* __restrict__ b2)
{
    int wave = threadIdx.x >> 6, lane = threadIdx.x & 63;
    long tok = (long)blockIdx.x * 4 + wave;
    int c0 = lane * 4;
    const short* xp = xbuf + tok * 256 + c0;
    float* yp = out + tok * 256 + c0;
    short xv[4];
    *(int2*)xv = *(const int2*)xp;
    float4 yv = *(const float4*)yp;
    float v[4]; float s = 0, ss = 0;
    v[0] = bf2f(xv[0]) + yv.x; v[1] = bf2f(xv[1]) + yv.y;
    v[2] = bf2f(xv[2]) + yv.z; v[3] = bf2f(xv[3]) + yv.w;
#pragma unroll
    for (int i = 0; i < 4; ++i) { s += v[i]; ss += v[i] * v[i]; }
#pragma unroll
    for (int off = 32; off > 0; off >>= 1) { s += __shfl_xor(s, off); ss += __shfl_xor(ss, off); }
    float mean = s * (1.0f / 256.0f);
    float rstd = rsqrtf(ss * (1.0f / 256.0f) - mean * mean + LN_EPS);
    float4 ov;
    ov.x = (v[0] - mean) * rstd * g2[c0 + 0] + b2[c0 + 0];
    ov.y = (v[1] - mean) * rstd * g2[c0 + 1] + b2[c0 + 1];
    ov.z = (v[2] - mean) * rstd * g2[c0 + 2] + b2[c0 + 2];
    ov.w = (v[3] - mean) * rstd * g2[c0 + 3] + b2[c0 + 3];
    *(float4*)yp = ov;
}

// ---------------------------------------------------------------------------
extern "C" void kernel_launch(void* const* d_in, const int* in_sizes, int n_in,
                              void* d_out, int out_size, void* d_ws, size_t ws_size,
                              hipStream_t stream)
{
    const float* q    = (const float*)d_in[0];
    const float* kv   = (const float*)d_in[1];
    const float* wq_w = (const float*)d_in[2];
    const float* wq_b = (const float*)d_in[3];
    const float* wk_w = (const float*)d_in[4];
    const float* wk_b = (const float*)d_in[5];
    const float* wv_w = (const float*)d_in[6];
    const float* wv_b = (const float*)d_in[7];
    const float* ln1g = (const float*)d_in[8];
    const float* ln1b = (const float*)d_in[9];
    const float* ff1w = (const float*)d_in[10];
    const float* ff1b = (const float*)d_in[11];
    const float* ff2w = (const float*)d_in[12];
    const float* ff2b = (const float*)d_in[13];
    const float* ln2g = (const float*)d_in[14];
    const float* ln2b = (const float*)d_in[15];

    char* w = (char*)d_ws;
    short* Wtq = (short*)w; w += 131072;           // [256][256] bf16
    short* Wtk = (short*)w; w += 131072;
    short* Wtv = (short*)w; w += 131072;
    short* Wt1 = (short*)w; w += 524288;           // [1024][256] bf16
    short* Wt2 = (short*)w; w += 524288;           // [256][1024] bf16
    float* pm  = (float*)w; w += 262144;           // [2][128][256] f32
    float* ps  = (float*)w; w += 262144;
    float* kmx = (float*)w; w += 2048;             // [2][256] f32
    float* ksm = (float*)w; w += 2048;
    float* ctx = (float*)w; w += 65536;            // [2][8][32][32] f32
    short* xbuf= (short*)w; w += 33554432;         // [65536][256] bf16
    short* QKV = (short*)w; w += 134217728;        // [65536][768] bf16; union w/ h1
    short* h1  = QKV;                              // [65536][1024] bf16 (QKV dead then)
    float* y   = (float*)d_out;                    // ff2 output fp32, LN2 in-place

    dim3 tb(32, 8);
    transpose_k<<<dim3(8, 8),  tb, 0, stream>>>(wq_w, Wtq, 256, 256);
    transpose_k<<<dim3(8, 8),  tb, 0, stream>>>(wk_w, Wtk, 256, 256);
    transpose_k<<<dim3(8, 8),  tb, 0, stream>>>(wv_w, Wtv, 256, 256);
    transpose_k<<<dim3(8, 32), tb, 0, stream>>>(ff1w, Wt1, 256, 1024);
    transpose_k<<<dim3(32, 8), tb, 0, stream>>>(ff2w, Wt2, 1024, 256);

    // Q/K/V projections (fp32 X -> bf16 staging) into interleaved [M][768]
    gemm_bt<0,1,0><<<dim3(2, 512), 256, 0, stream>>>(q,  Wtq, wq_b, QKV + 0,   256, 256, 256, 768);
    gemm_bt<0,1,0><<<dim3(2, 512), 256, 0, stream>>>(kv, Wtk, wk_b, QKV + 256, 256, 256, 256, 768);
    gemm_bt<0,1,0><<<dim3(2, 512), 256, 0, stream>>>(kv, Wtv, wv_b, QKV + 512, 256, 256, 256, 768);

    kstats_part<<<dim3(128, 2), 256, 0, stream>>>(QKV, pm, ps);
    kstats_fin<<<2, 256, 0, stream>>>(pm, ps, kmx, ksm);

    hipMemsetAsync(ctx, 0, 65536, stream);
    context_k<<<dim3(32, 8, 2), 256, 0, stream>>>(QKV, kmx, ctx);

    attn_ln1<<<512, 256, 0, stream>>>(QKV, q, ctx, ksm, ln1g, ln1b, xbuf);

    gemm_bt<1,0,0><<<dim3(8, 512), 256, 0, stream>>>(xbuf, Wt1, ff1b, h1, 1024, 256, 256, 1024);
    gemm_bt<0,0,1><<<dim3(2, 512), 256, 0, stream>>>(h1,  Wt2, ff2b, y,  256, 1024, 1024, 256);

    ln2_k<<<16384, 256, 0, stream>>>(xbuf, y, ln2g, ln2b);
}